// Round 11
// baseline (135.395 us; speedup 1.0000x reference)
//
#include <hip/hip_runtime.h>

#define NB 32
#define NS 512
#define NE 128
#define NU 10000

// ---- workspace layout (int units) ----
#define WS_PREVU 0                 // 16384
#define WS_PREVI 16384             // 16384
#define WS_RCNT  32768             // 3*32: per-(round,b) node counts
#define WS_LCNT  32864             // 32: per-b late counts
#define WS_GL    32896             // 3*32*512: per-(round,b) t-lists
#define WS_LATE  82048             // 32*512: per-b late t-lists
#define WS_WBF   98432             // 147456 ushorts (bf16 W_stack)

typedef __attribute__((ext_vector_type(8))) short bf16x8;
typedef __attribute__((ext_vector_type(4))) float f32x4;

__device__ __forceinline__ unsigned short f2bf(float f) {
    unsigned int u = __float_as_uint(f);
    u += 0x7fff + ((u >> 16) & 1);   // round-to-nearest-even
    return (unsigned short)(u >> 16);
}

// LDS-only barrier (no vmcnt drain; global ops stay in flight).
#define BARRIER() do { \
    asm volatile("s_waitcnt lgkmcnt(0)" ::: "memory"); \
    __builtin_amdgcn_s_barrier(); \
    __builtin_amdgcn_sched_barrier(0); \
} while (0)

// ---- kernel 1: per-b prep (blocks 0..31) + W->bf16 (blocks 32..67) ----
// Per b: prev tables (8-batched backward scans), parallel round relaxation
// (states 0,1,2,3=late-cap,255=unknown), per-b list build (no atomics across
// blocks; per-b private regions). Late (r>=3 or unresolved) kept t-ordered.
__global__ __launch_bounds__(512) void prep_kernel(
    const int* __restrict__ users, const int* __restrict__ items,
    const float* __restrict__ w_ih, const float* __restrict__ w_hh, int* ws)
{
    const int blk = blockIdx.x, tid = threadIdx.x;
    if (blk >= 32) {
        // convw: W_stack row R: R<384 -> w_ih[R,0:128]; R<768 ->
        // w_ih[R-384,128:256]; else w_hh[R-768,:]. 8 elems/thread.
        const int base = (blk - 32) * 4096 + tid * 8;
        const int r = base >> 7, k = base & 127;
        const float* src;
        if (r < 384)      src = w_ih + (size_t)r * 256 + k;
        else if (r < 768) src = w_ih + (size_t)(r - 384) * 256 + 128 + k;
        else              src = w_hh + (size_t)(r - 768) * 128 + k;
        unsigned short* wbf = (unsigned short*)(ws + WS_WBF);
#pragma unroll
        for (int j = 0; j < 8; ++j) wbf[base + j] = f2bf(src[j]);
        return;
    }
    const int b = blk;
    __shared__ int s_u[NS], s_i[NS];
    __shared__ unsigned char s_r[NS];
    __shared__ int cnt[3], s_chg;
    s_u[tid] = users[b * NS + tid];
    s_i[tid] = items[b * NS + tid];
    if (tid < 3) cnt[tid] = 0;
    __syncthreads();
    // backward prev scans, 8-batched to pipeline LDS latency
    const int mu = s_u[tid], mi = s_i[tid];
    int pu = -1, pi = -1;
    for (int u = tid - 1; u >= 0 && pu < 0; u -= 8) {
        int vals[8];
#pragma unroll
        for (int j = 0; j < 8; ++j) {
            const int uu = u - j;
            vals[j] = (uu >= 0) ? s_u[uu] : -1;
        }
#pragma unroll
        for (int j = 0; j < 8; ++j)
            if (pu < 0 && vals[j] == mu) pu = u - j;
    }
    for (int u = tid - 1; u >= 0 && pi < 0; u -= 8) {
        int vals[8];
#pragma unroll
        for (int j = 0; j < 8; ++j) {
            const int uu = u - j;
            vals[j] = (uu >= 0) ? s_i[uu] : -1;
        }
#pragma unroll
        for (int j = 0; j < 8; ++j)
            if (pi < 0 && vals[j] == mi) pi = u - j;
    }
    ws[WS_PREVU + (b << 9) + tid] = pu;
    ws[WS_PREVI + (b << 9) + tid] = pi;
    // round relaxation (monotone lattice; benign races; early exit)
    s_r[tid] = (pu < 0 && pi < 0) ? 0 : 255;
    __syncthreads();
    for (int pass = 0; pass < 16; ++pass) {
        if (tid == 0) s_chg = 0;
        __syncthreads();
        if (s_r[tid] == 255) {
            const int ru = pu < 0 ? -1 : (int)s_r[pu];
            const int ri = pi < 0 ? -1 : (int)s_r[pi];
            if (ru != 255 && ri != 255) {
                int rr = 1 + (ru > ri ? ru : ri);
                if (rr > 3) rr = 3;
                s_r[tid] = (unsigned char)rr;
                s_chg = 1;
            }
        }
        __syncthreads();
        if (!s_chg) break;
    }
    // per-b list build (atomics only within this block)
    const int r = s_r[tid];
    if (r < 3) {
        const int slot = atomicAdd(&cnt[r], 1);
        ws[WS_GL + (r * 32 + b) * 512 + slot] = tid;   // store t
    }
    __syncthreads();
    if (tid < 3) ws[WS_RCNT + tid * 32 + b] = cnt[tid];
    if (tid == 0) {   // late list in t-order (r>=3 incl. unresolved)
        int n = 0;
        for (int t = 0; t < NS; ++t)
            if (s_r[t] >= 3) { ws[WS_LATE + (b << 9) + n] = t; ++n; }
        ws[WS_LCNT + b] = n;
    }
}

// ---- kernel 2: batched GEMM+gates for round list r ----
// 256 blocks: b = blockIdx&31, sblk = blockIdx>>5 handles local chunks
// sblk, sblk+8, ... All metas computed upfront (parallel dependent chains),
// all <=8 chunk gathers issued into registers concurrently (latency paid
// once), then per chunk: LDS stage -> 36 MFMA/wave -> gates -> scatter h.
__global__ __launch_bounds__(512, 1) void round_gemm(
    const int* __restrict__ users, const int* __restrict__ items,
    const float* __restrict__ umem0, const float* __restrict__ imem0,
    const float* __restrict__ b_ih, const float* __restrict__ b_hh,
    const int* __restrict__ ws, float* uout, float* iout, int r)
{
    const int b = blockIdx.x & 31, sblk = blockIdx.x >> 5;
    const int cnt = ws[WS_RCNT + r * 32 + b];
    const int nch = (cnt + 7) >> 3;
    if (sblk >= nch) return;
    const int tid = threadIdx.x;
    const int lane = tid & 63, wave = tid >> 6;
    const int col = lane & 15, kgrp = lane >> 4;

    __shared__ __align__(16) float yl[16 * 1156];
    __shared__ __align__(16) float xf[16 * 132];
    __shared__ __align__(16) unsigned short xb[16 * 136];
    __shared__ float b6[768];
    __shared__ unsigned long long srcs[8][16];
    __shared__ unsigned long long hdst[8][16];

    for (int i = tid; i < 768; i += 512)
        b6[i] = i < 384 ? b_ih[i] : b_hh[i - 384];

    const unsigned short* wbf = (const unsigned short*)(ws + WS_WBF);
    bf16x8 wfrag[9][4];
#pragma unroll
    for (int m9 = 0; m9 < 9; ++m9) {
        const int row = wave * 144 + m9 * 16 + col;
#pragma unroll
        for (int kt = 0; kt < 4; ++kt)
            wfrag[m9][kt] = *(const bf16x8*)&wbf[row * 128 + kt * 32 + kgrp * 8];
    }

    const int* glist = ws + WS_GL + (r * 32 + b) * 512;
    const int* prevU = ws + WS_PREVU + (b << 9);
    const int* prevI = ws + WS_PREVI + (b << 9);

    // ---- all metas upfront: 128 threads, one (chunk k, col idx) each ----
    if (tid < 128) {
        const int k = tid >> 4, idx = tid & 15;
        const int lc = sblk + k * 8;
        unsigned long long sp = 0, hd = 0;
        if (lc < nch) {
            const int j = lc * 8 + (idx >> 1);
            if (j < cnt) {
                const int t = glist[j];
                const int node = (b << 9) + t;
                const int cell = idx & 1;
                const int p = cell ? prevI[t] : prevU[t];
                const float* s;
                if (p < 0) {
                    const int ix = cell ? items[node] : users[node];
                    s = (cell ? imem0 : umem0) + ((size_t)b * NU + ix) * NE;
                } else {
                    s = (cell ? iout : uout) + ((size_t)((b << 9) + p)) * NE;
                }
                sp = (unsigned long long)s;
                hd = (unsigned long long)((cell ? iout : uout) + (size_t)node * NE);
            }
        }
        srcs[k][idx] = sp; hdst[k][idx] = hd;
    }
    BARRIER();

    // ---- all gathers into registers, issued back-to-back ----
    const int gc = tid >> 5, ge4 = (tid & 31) * 4;
    float4 v[8];
#pragma unroll
    for (int k = 0; k < 8; ++k) {
        const float* s = (const float*)srcs[k][gc];
        v[k] = (float4){0.f, 0.f, 0.f, 0.f};
        if (s) v[k] = *(const float4*)(s + ge4);
    }

    // ---- per-chunk compute (static k indexing; rule #20) ----
#pragma unroll
    for (int k = 0; k < 8; ++k) {
        const int lc = sblk + k * 8;
        if (lc >= nch) break;
        // stage chunk k
        if (srcs[k][gc]) {
            *(float4*)&xf[gc * 132 + ge4] = v[k];
            ushort4 w4;
            w4.x = f2bf(v[k].x); w4.y = f2bf(v[k].y);
            w4.z = f2bf(v[k].z); w4.w = f2bf(v[k].w);
            *(ushort4*)&xb[gc * 136 + ge4] = w4;
        }
        BARRIER();
        {
            bf16x8 bfrag[4];
#pragma unroll
            for (int kt = 0; kt < 4; ++kt)
                bfrag[kt] = *(const bf16x8*)&xb[col * 136 + kt * 32 + kgrp * 8];
            f32x4 acc[9];
#pragma unroll
            for (int m9 = 0; m9 < 9; ++m9) acc[m9] = (f32x4){0.f, 0.f, 0.f, 0.f};
#pragma unroll
            for (int kt = 0; kt < 4; ++kt)
#pragma unroll
                for (int m9 = 0; m9 < 9; ++m9)
                    acc[m9] = __builtin_amdgcn_mfma_f32_16x16x32_bf16(
                        wfrag[m9][kt], bfrag[kt], acc[m9], 0, 0, 0);
#pragma unroll
            for (int m9 = 0; m9 < 9; ++m9)   // D: col=lane&15, row=kgrp*4+reg
                *(f32x4*)&yl[col * 1156 + wave * 144 + m9 * 16 + kgrp * 4] = acc[m9];
        }
        BARRIER();
#pragma unroll
        for (int it = 0; it < 4; ++it) {
            const int idx = tid + it * 512;
            const int c = idx >> 7, e = idx & 127;
            float* hb = (float*)hdst[k][c];
            if (hb) {
                const float* ys = &yl[c * 1156];
                const float* yo = &yl[(c ^ 1) * 1156];
                const float gir = ys[e]        + yo[384 + e] + b6[e];
                const float giz = ys[128 + e]  + yo[512 + e] + b6[128 + e];
                const float gin = ys[256 + e]  + yo[640 + e] + b6[256 + e];
                const float ghr = ys[768 + e]  + b6[384 + e];
                const float ghz = ys[896 + e]  + b6[512 + e];
                const float ghn = ys[1024 + e] + b6[640 + e];
                const float rr = 1.f / (1.f + __expf(-(gir + ghr)));
                const float z  = 1.f / (1.f + __expf(-(giz + ghz)));
                const float pre = gin + rr * ghn;
                const float n = 2.f / (1.f + __expf(-2.f * pre)) - 1.f;  // tanh
                hb[e] = (1.f - z) * n + z * xf[c * 132 + e];
            }
        }
        BARRIER();
    }
}

// ---- kernel 3: late nodes (r>=3), block b in t-order (normally empty) ----
__global__ __launch_bounds__(512, 1) void cleanup_kernel(
    const int* __restrict__ users, const int* __restrict__ items,
    const float* __restrict__ umem0, const float* __restrict__ imem0,
    const float* __restrict__ b_ih, const float* __restrict__ b_hh,
    const int* __restrict__ ws, float* uout, float* iout)
{
    const int b = blockIdx.x;
    const int n = ws[WS_LCNT + b];
    if (n == 0) return;
    const int tid = threadIdx.x;
    const int lane = tid & 63, wave = tid >> 6;
    const int col = lane & 15, kgrp = lane >> 4;

    __shared__ __align__(16) float yl[2][1156];
    __shared__ __align__(16) float xf[2][132];
    __shared__ __align__(16) unsigned short xb[2][136];
    __shared__ float b6[768];
    __shared__ const float* srcs[2];

    for (int i = tid; i < 768; i += 512)
        b6[i] = i < 384 ? b_ih[i] : b_hh[i - 384];

    const unsigned short* wbf = (const unsigned short*)(ws + WS_WBF);
    bf16x8 wfrag[9][4];
#pragma unroll
    for (int m9 = 0; m9 < 9; ++m9) {
        const int row = wave * 144 + m9 * 16 + col;
#pragma unroll
        for (int kt = 0; kt < 4; ++kt)
            wfrag[m9][kt] = *(const bf16x8*)&wbf[row * 128 + kt * 32 + kgrp * 8];
    }

    const int* prevU = ws + WS_PREVU + (b << 9);
    const int* prevI = ws + WS_PREVI + (b << 9);

    for (int k = 0; k < n; ++k) {
        const int t = ws[WS_LATE + (b << 9) + k];
        const int node = (b << 9) + t;
        if (tid < 2) {
            const int cell = tid;
            const int p = cell ? prevI[t] : prevU[t];
            const float* sp;
            if (p < 0) {
                const int ix = cell ? items[node] : users[node];
                sp = (cell ? imem0 : umem0) + ((size_t)b * NU + ix) * NE;
            } else {
                sp = (cell ? iout : uout) + ((size_t)((b << 9) + p)) * NE;
            }
            srcs[cell] = sp;
        }
        __syncthreads();
        if (tid < 64) {
            const int c = tid >> 5, e4 = (tid & 31) * 4;
            const float4 vv = *(const float4*)(srcs[c] + e4);
            *(float4*)&xf[c][e4] = vv;
            ushort4 w4;
            w4.x = f2bf(vv.x); w4.y = f2bf(vv.y);
            w4.z = f2bf(vv.z); w4.w = f2bf(vv.w);
            *(ushort4*)&xb[c][e4] = w4;
        }
        __syncthreads();
        {
            const int bc = col & 1;
            bf16x8 bfrag[4];
#pragma unroll
            for (int kt = 0; kt < 4; ++kt)
                bfrag[kt] = *(const bf16x8*)&xb[bc][kt * 32 + kgrp * 8];
            f32x4 acc[9];
#pragma unroll
            for (int m9 = 0; m9 < 9; ++m9) acc[m9] = (f32x4){0.f, 0.f, 0.f, 0.f};
#pragma unroll
            for (int kt = 0; kt < 4; ++kt)
#pragma unroll
                for (int m9 = 0; m9 < 9; ++m9)
                    acc[m9] = __builtin_amdgcn_mfma_f32_16x16x32_bf16(
                        wfrag[m9][kt], bfrag[kt], acc[m9], 0, 0, 0);
            if (col < 2) {
#pragma unroll
                for (int m9 = 0; m9 < 9; ++m9)
                    *(f32x4*)&yl[col][wave * 144 + m9 * 16 + kgrp * 4] = acc[m9];
            }
        }
        __syncthreads();
        if (tid < 256) {
            const int c = tid >> 7, e = tid & 127;
            const float* ys = yl[c];
            const float* yo = yl[c ^ 1];
            const float gir = ys[e]        + yo[384 + e] + b6[e];
            const float giz = ys[128 + e]  + yo[512 + e] + b6[128 + e];
            const float gin = ys[256 + e]  + yo[640 + e] + b6[256 + e];
            const float ghr = ys[768 + e]  + b6[384 + e];
            const float ghz = ys[896 + e]  + b6[512 + e];
            const float ghn = ys[1024 + e] + b6[640 + e];
            const float rr = 1.f / (1.f + __expf(-(gir + ghr)));
            const float z  = 1.f / (1.f + __expf(-(giz + ghz)));
            const float pre = gin + rr * ghn;
            const float nn = 2.f / (1.f + __expf(-2.f * pre)) - 1.f;
            (c ? iout : uout)[(size_t)node * NE + e] =
                (1.f - z) * nn + z * xf[c][e];
        }
        __threadfence();
        __syncthreads();
    }
}

extern "C" void kernel_launch(void* const* d_in, const int* in_sizes, int n_in,
                              void* d_out, int out_size, void* d_ws, size_t ws_size,
                              hipStream_t stream) {
    const int*   users = (const int*)d_in[0];
    const int*   items = (const int*)d_in[1];
    const float* umem0 = (const float*)d_in[2];
    const float* imem0 = (const float*)d_in[3];
    const float* w_ih  = (const float*)d_in[4];
    const float* w_hh  = (const float*)d_in[5];
    const float* b_ih  = (const float*)d_in[6];
    const float* b_hh  = (const float*)d_in[7];

    float* uout = (float*)d_out;
    float* iout = uout + (size_t)NB * NS * NE;
    int* ws = (int*)d_ws;

    prep_kernel<<<68, 512, 0, stream>>>(users, items, w_ih, w_hh, ws);
    round_gemm<<<256, 512, 0, stream>>>(users, items, umem0, imem0,
                                        b_ih, b_hh, ws, uout, iout, 0);
    round_gemm<<<256, 512, 0, stream>>>(users, items, umem0, imem0,
                                        b_ih, b_hh, ws, uout, iout, 1);
    round_gemm<<<256, 512, 0, stream>>>(users, items, umem0, imem0,
                                        b_ih, b_hh, ws, uout, iout, 2);
    cleanup_kernel<<<NB, 512, 0, stream>>>(users, items, umem0, imem0,
                                           b_ih, b_hh, ws, uout, iout);
}